// Round 8
// baseline (304.096 us; speedup 1.0000x reference)
//
#include <hip/hip_runtime.h>

typedef unsigned short u16;
typedef unsigned int uint;
typedef short bf16x8 __attribute__((ext_vector_type(8)));
typedef float f32x4 __attribute__((ext_vector_type(4)));

constexpr int B_ = 2;
constexpr int N_ = 40000;
constexpr int SPB = 240000;            // samples per batch = N*6
constexpr int S_ = B_ * SPB;           // 480000 BN samples
constexpr float EPS_ = 1e-5f;
constexpr float INV_S = 1.0f / (float)S_;
constexpr int OF_ = B_ * N_;           // out_feature elems before new_feature

// ws (u16 units): V bf16 [B*N][128] @0 (=raw-max region in big path; V dead after p1)
//   big: z0 bf16 [B*SPB][64] @10,240,000..40,960,000; stats f32@u16 40,960,000; pack@40,961,152
//   small: stats f32@u16 10,240,000; pack@10,241,152
constexpr int      WS_V_U16   = B_ * N_ * 128;
constexpr size_t   NEED_BIG_B = 81955072ull;

// ---------- helpers ----------
__device__ inline float b2f_lo(uint u) { return __builtin_bit_cast(float, u << 16); }
__device__ inline float b2f_hi(uint u) { return __builtin_bit_cast(float, u & 0xffff0000u); }
__device__ inline float b2fu(u16 s)    { return __builtin_bit_cast(float, ((uint)s) << 16); }
__device__ inline u16 f2b(float f) {   // RNE float->bf16
    uint b = __builtin_bit_cast(uint, f);
    return (u16)((b + 0x7fffu + ((b >> 16) & 1u)) >> 16);
}
__device__ inline uint pk2(float a, float b) { return (uint)f2b(a) | ((uint)f2b(b) << 16); }
__device__ inline void unp8(uint4 q, float* f) {
    f[0] = b2f_lo(q.x); f[1] = b2f_hi(q.x); f[2] = b2f_lo(q.y); f[3] = b2f_hi(q.y);
    f[4] = b2f_lo(q.z); f[5] = b2f_hi(q.z); f[6] = b2f_lo(q.w); f[7] = b2f_hi(q.w);
}

// ---------------- WPREP ----------------
__global__ __launch_bounds__(256) void wprep_kernel(const float* __restrict__ W0,
                                                    const float* __restrict__ W1,
                                                    const float* __restrict__ W2,
                                                    float* __restrict__ stats,
                                                    float* __restrict__ neg2,
                                                    u16* __restrict__ pack) {
    const int t = threadIdx.x;
    stats[t] = 0.f; stats[t + 256] = 0.f;
    if (t < 64) {
        float s = 0.f;
        for (int j = 0; j < 64; ++j) s += W0[t * 128 + 64 + j];
        neg2[t] = -s;
    }
    for (int g = t; g < 40 * 64; g += 256) {
        int lane = g & 63, grp = g >> 6;
        int cb = lane & 15, kq = lane >> 4;
        ushort4 lo, hi;
        u16* dst;
        if (grp < 16) {
            int ct = grp >> 1, kk = grp & 1;
            int c = ct * 16 + cb, jb = kk * 32 + kq * 8;
            dst = pack + g * 8;
            float v[8];
            #pragma unroll
            for (int i = 0; i < 8; ++i)
                v[i] = (c < 64) ? W0[c * 128 + jb + i] : W0[(c - 64) * 128 + 64 + jb + i];
            lo = {f2b(v[0]), f2b(v[1]), f2b(v[2]), f2b(v[3])};
            hi = {f2b(v[4]), f2b(v[5]), f2b(v[6]), f2b(v[7])};
        } else if (grp < 24) {
            int g2 = grp - 16;
            int ct = g2 >> 1, kk = g2 & 1;
            const float* wp = W1 + (ct * 16 + cb) * 64 + kk * 32 + kq * 8;
            dst = pack + 8192 + (g2 * 64 + lane) * 8;
            lo = {f2b(wp[0]), f2b(wp[1]), f2b(wp[2]), f2b(wp[3])};
            hi = {f2b(wp[4]), f2b(wp[5]), f2b(wp[6]), f2b(wp[7])};
        } else {
            int g3 = grp - 24;
            int ct = g3 >> 1, kk = g3 & 1;
            const float* wp = W2 + (ct * 16 + cb) * 64 + kk * 32 + kq * 8;
            dst = pack + 12288 + (g3 * 64 + lane) * 8;
            lo = {f2b(wp[0]), f2b(wp[1]), f2b(wp[2]), f2b(wp[3])};
            hi = {f2b(wp[4]), f2b(wp[5]), f2b(wp[6]), f2b(wp[7])};
        }
        *(ushort4*)dst = lo;
        *(ushort4*)(dst + 4) = hi;
    }
}

// ---------------- P0 (MFMA): V = M @ x ----------------
__global__ __launch_bounds__(256) void p0_kernel(const float* __restrict__ pts,
                                                 const u16* __restrict__ pack,
                                                 u16* __restrict__ V) {
    const int t = threadIdx.x, lane = t & 63, w = t >> 6;
    const int cb = lane & 15, kq = lane >> 4;
    const int b = blockIdx.y;
    const int n0 = blockIdx.x * 192 + w * 48;
    const uint4* mp = (const uint4*)pack;

    bf16x8 af[3][2];
    #pragma unroll
    for (int mt = 0; mt < 3; ++mt) {
        int n = n0 + mt * 16 + cb;
        int nc = (n < N_) ? n : (N_ - 1);
        const float* xp = pts + b * 64 * N_ + nc;
        #pragma unroll
        for (int kk = 0; kk < 2; ++kk) {
            int jb = kk * 32 + kq * 8;
            #pragma unroll
            for (int i = 0; i < 8; ++i)
                af[mt][kk][i] = (short)f2b(xp[(size_t)(jb + i) * N_]);
        }
    }
    #pragma unroll
    for (int ct = 0; ct < 8; ++ct) {
        bf16x8 b0 = __builtin_bit_cast(bf16x8, mp[(ct * 2 + 0) * 64 + lane]);
        bf16x8 b1 = __builtin_bit_cast(bf16x8, mp[(ct * 2 + 1) * 64 + lane]);
        #pragma unroll
        for (int mt = 0; mt < 3; ++mt) {
            f32x4 acc = {};
            acc = __builtin_amdgcn_mfma_f32_16x16x32_bf16(af[mt][0], b0, acc, 0, 0, 0);
            acc = __builtin_amdgcn_mfma_f32_16x16x32_bf16(af[mt][1], b1, acc, 0, 0, 0);
            int rbase = n0 + mt * 16 + kq * 4;
            #pragma unroll
            for (int r = 0; r < 4; ++r) {
                int n = rbase + r;
                if (n < N_) V[(size_t)(b * N_ + n) * 128 + ct * 16 + cb] = f2b(acc[r]);
            }
        }
    }
}

// ---------------- P1: gather once -> stats0 + store z0 rows [s][64] bf16 ----------------
template<int STOREZ0>
__global__ __launch_bounds__(256) void p1_kernel(const u16* __restrict__ V,
                                                 const int* __restrict__ nidx,
                                                 const float* __restrict__ neg2,
                                                 float* __restrict__ stats,
                                                 u16* __restrict__ z0) {
    const int t = threadIdx.x, lane = t & 63, w = t >> 6;
    const int slot = lane >> 3, cg = lane & 7;
    const int b = blockIdx.y;
    const int s0 = blockIdx.x * 384 + w * 96;
    uint4* zw = STOREZ0 ? ((uint4*)z0 + (size_t)b * SPB * 8) : nullptr;
    float ngs8[8];
    #pragma unroll
    for (int i = 0; i < 8; ++i) ngs8[i] = neg2[cg * 8 + i];
    float sum[8] = {0,0,0,0,0,0,0,0}, sq[8] = {0,0,0,0,0,0,0,0};
    #pragma unroll
    for (int h = 0; h < 2; ++h) {
        int mh[6]; uint4 q1[6], q2[6]; bool val[6];
        #pragma unroll
        for (int it = 0; it < 6; ++it) {
            int s = s0 + (h * 6 + it) * 8 + slot;
            mh[it] = nidx[s];
            q1[it] = *(const uint4*)(V + (size_t)(b * N_ + s / 6) * 128 + cg * 8);
        }
        #pragma unroll
        for (int it = 0; it < 6; ++it) {
            val[it] = (mh[it] < N_);
            int row2 = val[it] ? (b * N_ + mh[it]) : 0;
            q2[it] = *(const uint4*)(V + (size_t)row2 * 128 + 64 + cg * 8);
        }
        #pragma unroll
        for (int it = 0; it < 6; ++it) {
            float v1[8], v2[8], z[8];
            unp8(q1[it], v1); unp8(q2[it], v2);
            #pragma unroll
            for (int i = 0; i < 8; ++i) {
                z[i] = v1[i] + (val[it] ? v2[i] : ngs8[i]);
                sum[i] += z[i]; sq[i] = fmaf(z[i], z[i], sq[i]);
            }
            if constexpr (STOREZ0) {
                int s = s0 + (h * 6 + it) * 8 + slot;
                uint4 o = {pk2(z[0], z[1]), pk2(z[2], z[3]), pk2(z[4], z[5]), pk2(z[6], z[7])};
                zw[(size_t)s * 8 + cg] = o;
            }
        }
    }
    #pragma unroll
    for (int i = 0; i < 8; ++i) {
        sum[i] += __shfl_xor(sum[i], 8); sum[i] += __shfl_xor(sum[i], 16); sum[i] += __shfl_xor(sum[i], 32);
        sq[i]  += __shfl_xor(sq[i], 8);  sq[i]  += __shfl_xor(sq[i], 16);  sq[i]  += __shfl_xor(sq[i], 32);
    }
    __shared__ float red[2][4][64];
    if (slot == 0) {
        #pragma unroll
        for (int i = 0; i < 8; ++i) { red[0][w][cg * 8 + i] = sum[i]; red[1][w][cg * 8 + i] = sq[i]; }
    }
    __syncthreads();
    if (t < 64) {
        float s_ = (red[0][0][t] + red[0][1][t]) + (red[0][2][t] + red[0][3][t]);
        float q_ = (red[1][0][t] + red[1][1][t]) + (red[1][2][t] + red[1][3][t]);
        atomicAdd(&stats[t], s_);
        atomicAdd(&stats[64 + t], q_);
    }
}

// build A-frag from gathered V (small path)
__device__ inline bf16x8 build_af(const u16* __restrict__ V, int row1, int row2,
                                  const float* adt0, const float* adt1,
                                  const float* ngs, int j0) {
    float v1f[8], v2f[8];
    uint4 q1 = *(const uint4*)(V + (size_t)row1 * 128 + j0);
    unp8(q1, v1f);
    if (row2 >= 0) {
        uint4 q2 = *(const uint4*)(V + (size_t)row2 * 128 + 64 + j0);
        unp8(q2, v2f);
    } else {
        #pragma unroll
        for (int i = 0; i < 8; ++i) v2f[i] = ngs[j0 + i];
    }
    bf16x8 r;
    #pragma unroll
    for (int i = 0; i < 8; ++i) {
        float f0 = fmaxf((v1f[i] + v2f[i]) * adt0[j0 + i] + adt1[j0 + i], 0.f);
        r[i] = (short)f2b(f0);
    }
    return r;
}

// build A-frag from z0 row window (big path); q pair = z0 channels [kq*8..+8), [32+kq*8..+8)
__device__ inline void af_from_z0(uint4 q1, uint4 q2, int kq,
                                  const float* adt0, const float* adt1, bf16x8* af) {
    float z1[8], z2[8];
    unp8(q1, z1); unp8(q2, z2);
    bf16x8 a0, a1;
    #pragma unroll
    for (int i = 0; i < 8; ++i) {
        a0[i] = (short)f2b(fmaxf(z1[i] * adt0[kq * 8 + i] + adt1[kq * 8 + i], 0.f));
        a1[i] = (short)f2b(fmaxf(z2[i] * adt0[32 + kq * 8 + i] + adt1[32 + kq * 8 + i], 0.f));
    }
    af[0] = a0; af[1] = a1;
}

// sigma: A-row (mt, row) -> sample offset within wave's 48 samples
__device__ inline int sigma_sl(int mt, int row) {
    int r_ = row & 3, kqr = row >> 2;
    int idx = mt * 4 + r_;
    int po = (idx >= 6) ? 1 : 0;
    return (kqr * 2 + po) * 6 + (idx - 6 * po);
}

// ---------------- P2 big: z0 stream -> f0 -> z1 (MFMA), stats1 only ----------------
__global__ __launch_bounds__(256) void p2big_kernel(const u16* __restrict__ z0,
                                                    const u16* __restrict__ pack,
                                                    const float* __restrict__ g0,
                                                    const float* __restrict__ beta0,
                                                    float* __restrict__ stats) {
    __shared__ float adt0[64], adt1[64];
    __shared__ float red[2][4][64];
    const int t = threadIdx.x, lane = t & 63, w = t >> 6;
    const int cb = lane & 15, kq = lane >> 4;
    if (t < 64) {
        float mu = stats[t] * INV_S, vr = stats[64 + t] * INV_S - mu * mu;
        float a = rsqrtf(vr + EPS_) * g0[t];
        adt0[t] = a; adt1[t] = beta0[t] - mu * a;
    }
    __syncthreads();
    const int b = blockIdx.y;
    const int slb = blockIdx.x * 192 + w * 48;
    const uint4* zr = (const uint4*)z0 + (size_t)(b * SPB + slb) * 8;
    const uint4* w1p = (const uint4*)(pack + 8192);

    uint4 zq[6];
    #pragma unroll
    for (int mt = 0; mt < 3; ++mt) {
        int sig = sigma_sl(mt, cb);
        zq[mt * 2 + 0] = zr[sig * 8 + kq];
        zq[mt * 2 + 1] = zr[sig * 8 + 4 + kq];
    }
    bf16x8 bf[4][2];
    #pragma unroll
    for (int ct = 0; ct < 4; ++ct)
        #pragma unroll
        for (int kk = 0; kk < 2; ++kk)
            bf[ct][kk] = __builtin_bit_cast(bf16x8, w1p[(ct * 2 + kk) * 64 + lane]);

    float ssum[4] = {0,0,0,0}, ssq[4] = {0,0,0,0};
    #pragma unroll
    for (int mt = 0; mt < 3; ++mt) {
        bf16x8 af[2];
        af_from_z0(zq[mt * 2], zq[mt * 2 + 1], kq, adt0, adt1, af);
        f32x4 acc[4] = {};
        #pragma unroll
        for (int ct = 0; ct < 4; ++ct) {
            acc[ct] = __builtin_amdgcn_mfma_f32_16x16x32_bf16(af[0], bf[ct][0], acc[ct], 0, 0, 0);
            acc[ct] = __builtin_amdgcn_mfma_f32_16x16x32_bf16(af[1], bf[ct][1], acc[ct], 0, 0, 0);
        }
        #pragma unroll
        for (int ct = 0; ct < 4; ++ct)
            #pragma unroll
            for (int r = 0; r < 4; ++r) {
                float z = acc[ct][r];
                ssum[ct] += z; ssq[ct] = fmaf(z, z, ssq[ct]);
            }
    }
    #pragma unroll
    for (int ct = 0; ct < 4; ++ct) {
        ssum[ct] += __shfl_xor(ssum[ct], 16); ssum[ct] += __shfl_xor(ssum[ct], 32);
        ssq[ct]  += __shfl_xor(ssq[ct], 16);  ssq[ct]  += __shfl_xor(ssq[ct], 32);
    }
    if (lane < 16) {
        #pragma unroll
        for (int ct = 0; ct < 4; ++ct) {
            red[0][w][ct * 16 + lane] = ssum[ct];
            red[1][w][ct * 16 + lane] = ssq[ct];
        }
    }
    __syncthreads();
    if (t < 64) {
        float s = (red[0][0][t] + red[0][1][t]) + (red[0][2][t] + red[0][3][t]);
        float q = (red[1][0][t] + red[1][1][t]) + (red[1][2][t] + red[1][3][t]);
        atomicAdd(&stats[128 + t], s);
        atomicAdd(&stats[192 + t], q);
    }
}

// ---------------- P3 big: z0 stream -> f0 -> z1 -> f1 -> z2, stats2, k-max -> raw bf16 ----------------
__global__ __launch_bounds__(256) void p3big_kernel(const u16* __restrict__ z0,
                                                    const u16* __restrict__ pack,
                                                    const float* __restrict__ g0, const float* __restrict__ beta0,
                                                    const float* __restrict__ g1, const float* __restrict__ beta1,
                                                    const float* __restrict__ g2,
                                                    float* __restrict__ stats,
                                                    u16* __restrict__ raw) {
    __shared__ u16   f1t[4][1024];           // per-wave 16x64 bf16, XOR-swizzled, reused per mt
    __shared__ float smax[32][129];
    __shared__ float red[2][4][128];
    __shared__ float adt0s[64], adt1s[64], adt2s[64], adt3s[64], psign[128];
    const int t = threadIdx.x, lane = t & 63, w = t >> 6;
    const int cb = lane & 15, kq = lane >> 4;
    if (t < 64) {
        float mu0 = stats[t] * INV_S, vr0 = stats[64 + t] * INV_S - mu0 * mu0;
        float a0 = rsqrtf(vr0 + EPS_) * g0[t];
        adt0s[t] = a0; adt1s[t] = beta0[t] - mu0 * a0;
        float mu1 = stats[128 + t] * INV_S, vr1 = stats[192 + t] * INV_S - mu1 * mu1;
        float a1 = rsqrtf(vr1 + EPS_) * g1[t];
        adt2s[t] = a1; adt3s[t] = beta1[t] - mu1 * a1;
    }
    if (t < 128) psign[t] = (g2[t] >= 0.f) ? 1.f : -1.f;
    __syncthreads();

    const int b = blockIdx.y;
    const int slb = blockIdx.x * 192 + w * 48;
    const uint4* zr = (const uint4*)z0 + (size_t)(b * SPB + slb) * 8;
    const uint4* w1p = (const uint4*)(pack + 8192);
    const uint4* w2p = (const uint4*)(pack + 12288);

    uint4 zq[6];
    #pragma unroll
    for (int mt = 0; mt < 3; ++mt) {
        int sig = sigma_sl(mt, cb);
        zq[mt * 2 + 0] = zr[sig * 8 + kq];
        zq[mt * 2 + 1] = zr[sig * 8 + 4 + kq];
    }
    bf16x8 bf2[8][2];
    #pragma unroll
    for (int u = 0; u < 8; ++u)
        #pragma unroll
        for (int kk = 0; kk < 2; ++kk)
            bf2[u][kk] = __builtin_bit_cast(bf16x8, w2p[(u * 2 + kk) * 64 + lane]);

    float a1c[4], d1c[4];
    #pragma unroll
    for (int ct = 0; ct < 4; ++ct) { a1c[ct] = adt2s[ct * 16 + cb]; d1c[ct] = adt3s[ct * 16 + cb]; }

    float pmax_[2][4][2];
    #pragma unroll
    for (int h = 0; h < 2; ++h)
        #pragma unroll
        for (int ct = 0; ct < 4; ++ct) { pmax_[h][ct][0] = -3.402823466e+38f; pmax_[h][ct][1] = -3.402823466e+38f; }
    float ssum[8] = {0,0,0,0,0,0,0,0}, ssq[8] = {0,0,0,0,0,0,0,0};
    u16* fb = f1t[w];

    #pragma unroll
    for (int mt = 0; mt < 3; ++mt) {
        bf16x8 af[2];
        af_from_z0(zq[mt * 2], zq[mt * 2 + 1], kq, adt0s, adt1s, af);
        bf16x8 bf1[4][2];
        #pragma unroll
        for (int ct = 0; ct < 4; ++ct)
            #pragma unroll
            for (int kk = 0; kk < 2; ++kk)
                bf1[ct][kk] = __builtin_bit_cast(bf16x8, w1p[(ct * 2 + kk) * 64 + lane]);
        f32x4 z1v[4];
        #pragma unroll
        for (int ct = 0; ct < 4; ++ct) {
            f32x4 a = {};
            a = __builtin_amdgcn_mfma_f32_16x16x32_bf16(af[0], bf1[ct][0], a, 0, 0, 0);
            a = __builtin_amdgcn_mfma_f32_16x16x32_bf16(af[1], bf1[ct][1], a, 0, 0, 0);
            z1v[ct] = a;
        }
        #pragma unroll
        for (int ct = 0; ct < 4; ++ct)
            #pragma unroll
            for (int r = 0; r < 4; ++r) {
                float f1 = fmaxf(z1v[ct][r] * a1c[ct] + d1c[ct], 0.f);
                int rw = kq * 4 + r;
                fb[rw * 64 + ((ct * 16 + cb) ^ ((rw & 7) << 3))] = f2b(f1);
            }
        bf16x8 af2[2];
        #pragma unroll
        for (int kk = 0; kk < 2; ++kk) {
            int j0 = kk * 32 + kq * 8;
            af2[kk] = __builtin_bit_cast(bf16x8, *(const uint4*)(fb + cb * 64 + (j0 ^ ((cb & 7) << 3))));
        }
        #pragma unroll
        for (int half = 0; half < 2; ++half) {
            f32x4 acc2[4] = {};
            #pragma unroll
            for (int ct = 0; ct < 4; ++ct) {
                acc2[ct] = __builtin_amdgcn_mfma_f32_16x16x32_bf16(af2[0], bf2[half * 4 + ct][0], acc2[ct], 0, 0, 0);
                acc2[ct] = __builtin_amdgcn_mfma_f32_16x16x32_bf16(af2[1], bf2[half * 4 + ct][1], acc2[ct], 0, 0, 0);
            }
            #pragma unroll
            for (int ct = 0; ct < 4; ++ct) {
                float ps = psign[half * 64 + ct * 16 + cb];
                #pragma unroll
                for (int r = 0; r < 4; ++r) {
                    float z = acc2[ct][r];
                    ssum[half * 4 + ct] += z;
                    ssq[half * 4 + ct] = fmaf(z, z, ssq[half * 4 + ct]);
                    float zz = z * ps;
                    int pi = (mt == 0) ? 0 : ((mt == 2) ? 1 : ((r >= 2) ? 1 : 0));
                    pmax_[half][ct][pi] = fmaxf(pmax_[half][ct][pi], zz);
                }
            }
        }
    }
    #pragma unroll
    for (int half = 0; half < 2; ++half)
        #pragma unroll
        for (int ct = 0; ct < 4; ++ct)
            #pragma unroll
            for (int p = 0; p < 2; ++p)
                smax[w * 8 + kq * 2 + p][half * 64 + ct * 16 + cb] = pmax_[half][ct][p];
    #pragma unroll
    for (int j = 0; j < 8; ++j) {
        ssum[j] += __shfl_xor(ssum[j], 16); ssum[j] += __shfl_xor(ssum[j], 32);
        ssq[j]  += __shfl_xor(ssq[j], 16);  ssq[j]  += __shfl_xor(ssq[j], 32);
    }
    if (lane < 16) {
        #pragma unroll
        for (int j = 0; j < 8; ++j) {
            int c = (j >> 2) * 64 + (j & 3) * 16 + lane;
            red[0][w][c] = ssum[j];
            red[1][w][c] = ssq[j];
        }
    }
    __syncthreads();
    if (t < 128) {
        float s = (red[0][0][t] + red[0][1][t]) + (red[0][2][t] + red[0][3][t]);
        float q = (red[1][0][t] + red[1][1][t]) + (red[1][2][t] + red[1][3][t]);
        atomicAdd(&stats[256 + t], s);
        atomicAdd(&stats[384 + t], q);
    }
    {
        int c2 = t >> 1, nh = t & 1;
        float ps = psign[c2];
        u16* rp = raw + ((size_t)b * 128 + c2) * N_ + blockIdx.x * 32 + nh * 16;
        #pragma unroll
        for (int i4 = 0; i4 < 4; ++i4) {
            ushort4 v;
            v.x = f2b(smax[nh * 16 + i4 * 4 + 0][c2] * ps);
            v.y = f2b(smax[nh * 16 + i4 * 4 + 1][c2] * ps);
            v.z = f2b(smax[nh * 16 + i4 * 4 + 2][c2] * ps);
            v.w = f2b(smax[nh * 16 + i4 * 4 + 3][c2] * ps);
            *(ushort4*)(rp + i4 * 4) = v;
        }
    }
}

// ---------------- small-path P2/P3 (gather recompute, round-7 logic) ----------------
__global__ __launch_bounds__(256) void p2small_kernel(const u16* __restrict__ V,
                                                      const int* __restrict__ nidx,
                                                      const float* __restrict__ neg2,
                                                      const u16* __restrict__ pack,
                                                      const float* __restrict__ g0,
                                                      const float* __restrict__ beta0,
                                                      float* __restrict__ stats) {
    __shared__ float adt0[64], adt1[64], ngs[64];
    __shared__ float red[2][4][64];
    const int t = threadIdx.x, lane = t & 63, w = t >> 6;
    const int cb = lane & 15, kq = lane >> 4;
    if (t < 64) {
        float mu = stats[t] * INV_S, vr = stats[64 + t] * INV_S - mu * mu;
        float a = rsqrtf(vr + EPS_) * g0[t];
        adt0[t] = a; adt1[t] = beta0[t] - mu * a; ngs[t] = neg2[t];
    }
    __syncthreads();
    const int b = blockIdx.y;
    const int slb = blockIdx.x * 192 + w * 48;
    const uint4* w1p = (const uint4*)(pack + 8192);
    bf16x8 bf[4][2];
    #pragma unroll
    for (int ct = 0; ct < 4; ++ct)
        #pragma unroll
        for (int kk = 0; kk < 2; ++kk)
            bf[ct][kk] = __builtin_bit_cast(bf16x8, w1p[(ct * 2 + kk) * 64 + lane]);
    float ssum[4] = {0,0,0,0}, ssq[4] = {0,0,0,0};
    #pragma unroll
    for (int mt = 0; mt < 3; ++mt) {
        int sl = slb + sigma_sl(mt, cb);
        int n = sl / 6;
        int m = nidx[sl];
        int row1 = b * N_ + n;
        int row2 = (m < N_) ? (b * N_ + m) : -1;
        bf16x8 af[2];
        #pragma unroll
        for (int kk = 0; kk < 2; ++kk)
            af[kk] = build_af(V, row1, row2, adt0, adt1, ngs, kk * 32 + kq * 8);
        f32x4 acc[4] = {};
        #pragma unroll
        for (int ct = 0; ct < 4; ++ct) {
            acc[ct] = __builtin_amdgcn_mfma_f32_16x16x32_bf16(af[0], bf[ct][0], acc[ct], 0, 0, 0);
            acc[ct] = __builtin_amdgcn_mfma_f32_16x16x32_bf16(af[1], bf[ct][1], acc[ct], 0, 0, 0);
        }
        #pragma unroll
        for (int ct = 0; ct < 4; ++ct)
            #pragma unroll
            for (int r = 0; r < 4; ++r) {
                float z = acc[ct][r];
                ssum[ct] += z; ssq[ct] = fmaf(z, z, ssq[ct]);
            }
    }
    #pragma unroll
    for (int ct = 0; ct < 4; ++ct) {
        ssum[ct] += __shfl_xor(ssum[ct], 16); ssum[ct] += __shfl_xor(ssum[ct], 32);
        ssq[ct]  += __shfl_xor(ssq[ct], 16);  ssq[ct]  += __shfl_xor(ssq[ct], 32);
    }
    if (lane < 16) {
        #pragma unroll
        for (int ct = 0; ct < 4; ++ct) {
            red[0][w][ct * 16 + lane] = ssum[ct];
            red[1][w][ct * 16 + lane] = ssq[ct];
        }
    }
    __syncthreads();
    if (t < 64) {
        float s = (red[0][0][t] + red[0][1][t]) + (red[0][2][t] + red[0][3][t]);
        float q = (red[1][0][t] + red[1][1][t]) + (red[1][2][t] + red[1][3][t]);
        atomicAdd(&stats[128 + t], s);
        atomicAdd(&stats[192 + t], q);
    }
}

__global__ __launch_bounds__(256) void p3small_kernel(const u16* __restrict__ V,
                                                      const int* __restrict__ nidx,
                                                      const float* __restrict__ neg2,
                                                      const u16* __restrict__ pack,
                                                      const float* __restrict__ g0, const float* __restrict__ beta0,
                                                      const float* __restrict__ g1, const float* __restrict__ beta1,
                                                      const float* __restrict__ g2,
                                                      float* __restrict__ stats,
                                                      float* __restrict__ out) {
    __shared__ u16   f1t[4][1024];
    __shared__ float smax[32][129];
    __shared__ float red[2][4][128];
    __shared__ float adt2s[64], adt3s[64], psign[128];
    __shared__ float adt0s[64], adt1s[64], ngs[64];
    const int t = threadIdx.x, lane = t & 63, w = t >> 6;
    const int cb = lane & 15, kq = lane >> 4;
    if (t < 64) {
        float mu1 = stats[128 + t] * INV_S, vr1 = stats[192 + t] * INV_S - mu1 * mu1;
        float a1 = rsqrtf(vr1 + EPS_) * g1[t];
        adt2s[t] = a1; adt3s[t] = beta1[t] - mu1 * a1;
        float mu0 = stats[t] * INV_S, vr0 = stats[64 + t] * INV_S - mu0 * mu0;
        float a0 = rsqrtf(vr0 + EPS_) * g0[t];
        adt0s[t] = a0; adt1s[t] = beta0[t] - mu0 * a0; ngs[t] = neg2[t];
    }
    if (t < 128) psign[t] = (g2[t] >= 0.f) ? 1.f : -1.f;
    __syncthreads();
    const int b = blockIdx.y;
    const int slb = blockIdx.x * 192 + w * 48;
    const uint4* w1p = (const uint4*)(pack + 8192);
    const uint4* w2p = (const uint4*)(pack + 12288);
    bf16x8 bf2[8][2];
    #pragma unroll
    for (int u = 0; u < 8; ++u)
        #pragma unroll
        for (int kk = 0; kk < 2; ++kk)
            bf2[u][kk] = __builtin_bit_cast(bf16x8, w2p[(u * 2 + kk) * 64 + lane]);
    float a1c[4], d1c[4];
    #pragma unroll
    for (int ct = 0; ct < 4; ++ct) { a1c[ct] = adt2s[ct * 16 + cb]; d1c[ct] = adt3s[ct * 16 + cb]; }
    float pmax_[2][4][2];
    #pragma unroll
    for (int h = 0; h < 2; ++h)
        #pragma unroll
        for (int ct = 0; ct < 4; ++ct) { pmax_[h][ct][0] = -3.402823466e+38f; pmax_[h][ct][1] = -3.402823466e+38f; }
    float ssum[8] = {0,0,0,0,0,0,0,0}, ssq[8] = {0,0,0,0,0,0,0,0};
    u16* fb = f1t[w];
    #pragma unroll
    for (int mt = 0; mt < 3; ++mt) {
        bf16x8 bf1[4][2];
        #pragma unroll
        for (int ct = 0; ct < 4; ++ct)
            #pragma unroll
            for (int kk = 0; kk < 2; ++kk)
                bf1[ct][kk] = __builtin_bit_cast(bf16x8, w1p[(ct * 2 + kk) * 64 + lane]);
        int sl = slb + sigma_sl(mt, cb);
        int n = sl / 6;
        int m = nidx[sl];
        int row1 = b * N_ + n;
        int row2 = (m < N_) ? (b * N_ + m) : -1;
        bf16x8 af[2];
        #pragma unroll
        for (int kk = 0; kk < 2; ++kk)
            af[kk] = build_af(V, row1, row2, adt0s, adt1s, ngs, kk * 32 + kq * 8);
        f32x4 z1v[4];
        #pragma unroll
        for (int ct = 0; ct < 4; ++ct) {
            f32x4 a = {};
            a = __builtin_amdgcn_mfma_f32_16x16x32_bf16(af[0], bf1[ct][0], a, 0, 0, 0);
            a = __builtin_amdgcn_mfma_f32_16x16x32_bf16(af[1], bf1[ct][1], a, 0, 0, 0);
            z1v[ct] = a;
        }
        #pragma unroll
        for (int ct = 0; ct < 4; ++ct)
            #pragma unroll
            for (int r = 0; r < 4; ++r) {
                float f1 = fmaxf(z1v[ct][r] * a1c[ct] + d1c[ct], 0.f);
                int rw = kq * 4 + r;
                fb[rw * 64 + ((ct * 16 + cb) ^ ((rw & 7) << 3))] = f2b(f1);
            }
        bf16x8 af2[2];
        #pragma unroll
        for (int kk = 0; kk < 2; ++kk) {
            int j0 = kk * 32 + kq * 8;
            af2[kk] = __builtin_bit_cast(bf16x8, *(const uint4*)(fb + cb * 64 + (j0 ^ ((cb & 7) << 3))));
        }
        #pragma unroll
        for (int half = 0; half < 2; ++half) {
            f32x4 acc2[4] = {};
            #pragma unroll
            for (int ct = 0; ct < 4; ++ct) {
                acc2[ct] = __builtin_amdgcn_mfma_f32_16x16x32_bf16(af2[0], bf2[half * 4 + ct][0], acc2[ct], 0, 0, 0);
                acc2[ct] = __builtin_amdgcn_mfma_f32_16x16x32_bf16(af2[1], bf2[half * 4 + ct][1], acc2[ct], 0, 0, 0);
            }
            #pragma unroll
            for (int ct = 0; ct < 4; ++ct) {
                float ps = psign[half * 64 + ct * 16 + cb];
                #pragma unroll
                for (int r = 0; r < 4; ++r) {
                    float z = acc2[ct][r];
                    ssum[half * 4 + ct] += z;
                    ssq[half * 4 + ct] = fmaf(z, z, ssq[half * 4 + ct]);
                    float zz = z * ps;
                    int pi = (mt == 0) ? 0 : ((mt == 2) ? 1 : ((r >= 2) ? 1 : 0));
                    pmax_[half][ct][pi] = fmaxf(pmax_[half][ct][pi], zz);
                }
            }
        }
    }
    #pragma unroll
    for (int half = 0; half < 2; ++half)
        #pragma unroll
        for (int ct = 0; ct < 4; ++ct)
            #pragma unroll
            for (int p = 0; p < 2; ++p)
                smax[w * 8 + kq * 2 + p][half * 64 + ct * 16 + cb] = pmax_[half][ct][p];
    #pragma unroll
    for (int j = 0; j < 8; ++j) {
        ssum[j] += __shfl_xor(ssum[j], 16); ssum[j] += __shfl_xor(ssum[j], 32);
        ssq[j]  += __shfl_xor(ssq[j], 16);  ssq[j]  += __shfl_xor(ssq[j], 32);
    }
    if (lane < 16) {
        #pragma unroll
        for (int j = 0; j < 8; ++j) {
            int c = (j >> 2) * 64 + (j & 3) * 16 + lane;
            red[0][w][c] = ssum[j];
            red[1][w][c] = ssq[j];
        }
    }
    __syncthreads();
    if (t < 128) {
        float s = (red[0][0][t] + red[0][1][t]) + (red[0][2][t] + red[0][3][t]);
        float q = (red[1][0][t] + red[1][1][t]) + (red[1][2][t] + red[1][3][t]);
        atomicAdd(&stats[256 + t], s);
        atomicAdd(&stats[384 + t], q);
    }
    {
        int c2 = t >> 1, nh = t & 1;
        float ps = psign[c2];
        float* op = out + OF_ + ((size_t)b * 128 + c2) * N_ + blockIdx.x * 32 + nh * 16;
        #pragma unroll
        for (int i4 = 0; i4 < 4; ++i4) {
            float4 v;
            v.x = smax[nh * 16 + i4 * 4 + 0][c2] * ps;
            v.y = smax[nh * 16 + i4 * 4 + 1][c2] * ps;
            v.z = smax[nh * 16 + i4 * 4 + 2][c2] * ps;
            v.w = smax[nh * 16 + i4 * 4 + 3][c2] * ps;
            *(float4*)(op + i4 * 4) = v;
        }
    }
}

// ---------------- P4 big / small ----------------
__global__ __launch_bounds__(256) void p4big_kernel(const float* __restrict__ g2,
                                                    const float* __restrict__ beta2,
                                                    const float* __restrict__ stats,
                                                    const u16* __restrict__ raw,
                                                    float* __restrict__ out) {
    __shared__ float a2s[128], d2s[128];
    __shared__ float vred[4][64];
    const int t = threadIdx.x, lane = t & 63, cg = t >> 6;
    if (t < 128) {
        float mu = stats[256 + t] * INV_S;
        float vr = stats[384 + t] * INV_S - mu * mu;
        float a = rsqrtf(vr + EPS_) * g2[t];
        a2s[t] = a;
        d2s[t] = beta2[t] - mu * a;
    }
    __syncthreads();
    const int b = blockIdx.y;
    const int n = blockIdx.x * 64 + lane;
    const u16* rp = raw + ((size_t)b * 128 + cg * 32) * N_ + n;
    float* op = out + OF_ + ((size_t)b * 128 + cg * 32) * N_ + n;
    float vmax = -3.402823466e+38f;
    #pragma unroll 8
    for (int c = 0; c < 32; ++c) {
        int c2 = cg * 32 + c;
        float v = fmaxf(b2fu(rp[(size_t)c * N_]) * a2s[c2] + d2s[c2], 0.f);
        op[(size_t)c * N_] = v;
        vmax = fmaxf(vmax, v);
    }
    vred[cg][lane] = vmax;
    __syncthreads();
    if (t < 64)
        out[b * N_ + blockIdx.x * 64 + t] =
            fmaxf(fmaxf(vred[0][t], vred[1][t]), fmaxf(vred[2][t], vred[3][t]));
}

__global__ __launch_bounds__(256) void p4small_kernel(const float* __restrict__ g2,
                                                      const float* __restrict__ beta2,
                                                      const float* __restrict__ stats,
                                                      float* __restrict__ outbuf) {
    __shared__ float a2s[128], d2s[128];
    const int t = threadIdx.x;
    if (t < 128) {
        float mu = stats[256 + t] * INV_S;
        float vr = stats[384 + t] * INV_S - mu * mu;
        float a = rsqrtf(vr + EPS_) * g2[t];
        a2s[t] = a;
        d2s[t] = beta2[t] - mu * a;
    }
    __syncthreads();
    const int b = blockIdx.y;
    const int n = blockIdx.x * 256 + t;
    if (n >= N_) return;
    float vmax = -3.402823466e+38f;
    #pragma unroll 8
    for (int c2 = 0; c2 < 128; ++c2) {
        size_t idx = OF_ + ((size_t)b * 128 + c2) * N_ + n;
        float v = fmaxf(outbuf[idx] * a2s[c2] + d2s[c2], 0.f);
        outbuf[idx] = v;
        vmax = fmaxf(vmax, v);
    }
    outbuf[b * N_ + n] = vmax;
}

extern "C" void kernel_launch(void* const* d_in, const int* in_sizes, int n_in,
                              void* d_out, int out_size, void* d_ws, size_t ws_size,
                              hipStream_t stream) {
    (void)in_sizes; (void)n_in; (void)out_size;
    const float* pts   = (const float*)d_in[0];
    const int*   nidx  = (const int*)d_in[1];
    const float* W0    = (const float*)d_in[2];
    const float* g0    = (const float*)d_in[4];
    const float* beta0 = (const float*)d_in[5];
    const float* W1    = (const float*)d_in[6];
    const float* g1    = (const float*)d_in[8];
    const float* beta1 = (const float*)d_in[9];
    const float* W2    = (const float*)d_in[10];
    const float* g2    = (const float*)d_in[12];
    const float* beta2 = (const float*)d_in[13];
    const bool big = ws_size >= NEED_BIG_B;
    u16*   V     = (u16*)d_ws;                 // doubles as bf16 raw-max buffer in big path
    u16*   z0b   = big ? ((u16*)d_ws + WS_V_U16) : nullptr;
    float* stats = (float*)d_ws + (big ? 20480000 : 5120000);
    float* neg2  = stats + 512;
    u16*   pack  = (u16*)d_ws + (big ? 40961152 : 10241152);
    float* out   = (float*)d_out;

    hipLaunchKernelGGL(wprep_kernel, dim3(1), dim3(256), 0, stream, W0, W1, W2, stats, neg2, pack);
    hipLaunchKernelGGL(p0_kernel, dim3((N_ + 191) / 192, B_), dim3(256), 0, stream, pts, pack, V);
    if (big) {
        hipLaunchKernelGGL((p1_kernel<1>), dim3(SPB / 384, B_), dim3(256), 0, stream, V, nidx, neg2, stats, z0b);
        hipLaunchKernelGGL(p2big_kernel, dim3(SPB / 192, B_), dim3(256), 0, stream, z0b, pack, g0, beta0, stats);
        hipLaunchKernelGGL(p3big_kernel, dim3(SPB / 192, B_), dim3(256), 0, stream,
                           z0b, pack, g0, beta0, g1, beta1, g2, stats, V);
        hipLaunchKernelGGL(p4big_kernel, dim3(N_ / 64, B_), dim3(256), 0, stream, g2, beta2, stats, V, out);
    } else {
        hipLaunchKernelGGL((p1_kernel<0>), dim3(SPB / 384, B_), dim3(256), 0, stream, V, nidx, neg2, stats, nullptr);
        hipLaunchKernelGGL(p2small_kernel, dim3(SPB / 192, B_), dim3(256), 0, stream,
                           V, nidx, neg2, pack, g0, beta0, stats);
        hipLaunchKernelGGL(p3small_kernel, dim3(SPB / 192, B_), dim3(256), 0, stream,
                           V, nidx, neg2, pack, g0, beta0, g1, beta1, g2, stats, out);
        hipLaunchKernelGGL(p4small_kernel, dim3((N_ + 255) / 256, B_), dim3(256), 0, stream,
                           g2, beta2, stats, out);
    }
}